// Round 3
// baseline (1156.218 us; speedup 1.0000x reference)
//
#include <hip/hip_runtime.h>

// VQExpert fused kernel for MI355X (gfx950).
//
// Algebraic collapse:
//   z = x @ Wc.T + bc            where Wc = W_pin@W_down  [32,128], bc = W_pin@b_down + b_pin
//   idx = argmax_c (z . C[c] - 0.5|C[c]|^2)   (== argmin d2, first-min tie-break)
//   y = Y_table[idx]             where Y_table[c] = clip((C[c]@W_pout.T+b_pout)@W_up.T+b_up, -1, 1)
//
// d_out layout (all float32): y [N*128] | indices-as-float [N] | commit_loss [1]
//
// R3: R2's architecture (LDS codebook broadcast, 2 rows/thread, 2 blocks/CU)
// but score arithmetic restored TOKEN-IDENTICAL to the R1 kernel that passed:
// R2's re-associated chain (c.x*a0 + c.y*a1 + ...) changed fp rounding and
// flipped near-tie argmins (indices absmax 220). Indices require exact match;
// keep the 4 strided fmac chains + ((s0+s1)+(s2+s3))+bias reduction + in-order
// compare chain. Do NOT re-associate the score loop.

#define CODE_D 32
#define NUM_C  256
#define KCH    32
#define LSTR   36   // LDS x-tile row stride in floats (32 + 4 pad) = 144 B; measured 0 conflicts

// ---------------- prep kernels (rebuilt every launch; ws is re-poisoned) ------------

__global__ void vq_prep1(const float* __restrict__ Wd, const float* __restrict__ bd,
                         const float* __restrict__ Wp, const float* __restrict__ bp,
                         const float* __restrict__ cb,
                         float* __restrict__ Wc, float* __restrict__ bc,
                         float* __restrict__ cbias) {
    const int t = threadIdx.x;   // 256 threads, 17 blocks
    const int b = blockIdx.x;
    if (b < 16) {
        // Wc[j][k] = sum_m Wp[j][m] * Wd[m][k]  (double accum for fidelity); 1 elem/thread
        const int e = b * 256 + t;
        const int j = e >> 7, k = e & 127;
        double s = 0.0;
        for (int m = 0; m < 128; ++m)
            s += (double)Wp[j * 128 + m] * (double)Wd[m * 128 + k];
        Wc[e] = (float)s;
    } else {
        if (t < 32) {
            double s = (double)bp[t];
            for (int m = 0; m < 128; ++m) s += (double)Wp[t * 128 + m] * (double)bd[m];
            bc[t] = (float)s;
        }
        // cbias[c] = -0.5 * |C[c]|^2
        float s = 0.f;
        for (int d = 0; d < CODE_D; ++d) { float v = cb[t * CODE_D + d]; s += v * v; }
        cbias[t] = -0.5f * s;
    }
}

__global__ void vq_prep2(const float* __restrict__ cb, const float* __restrict__ Wpo,
                         const float* __restrict__ bpo, const float* __restrict__ Wu,
                         const float* __restrict__ bu, float* __restrict__ ytab) {
    __shared__ float v[128];
    const int c = blockIdx.x;    // 256 blocks
    const int t = threadIdx.x;   // 128 threads
    float s = bpo[t];
    for (int d = 0; d < CODE_D; ++d) s += cb[c * CODE_D + d] * Wpo[t * CODE_D + d];
    v[t] = s;
    __syncthreads();
    float o = bu[t];
    for (int m = 0; m < 128; ++m) o += v[m] * Wu[t * 128 + m];
    o = fminf(fmaxf(o, -1.0f), 1.0f);
    ytab[c * 128 + t] = o;
}

// ---------------- main fused kernel ------------------------------------------------

__global__ __launch_bounds__(256, 2) void vq_main(
    const float* __restrict__ x,      // [N,128]
    const float* __restrict__ Wc,     // [32,128]
    const float* __restrict__ bc,     // [32]
    const float* __restrict__ cb,     // codebook [256,32]
    const float* __restrict__ cbias,  // [256]
    const float* __restrict__ ytab,   // [256,128]
    float* __restrict__ y,            // [N,128]
    float* __restrict__ idx_out,      // [N] (written as float values)
    float* __restrict__ loss_out,     // [1]
    int N) {
    __shared__ float xs[256 * LSTR];      // 36 KB x-tile (256 rows x 32 cols, padded)
    __shared__ float cbs[NUM_C * CODE_D]; // 32 KB codebook
    __shared__ float cbb[NUM_C];          // 1 KB  -0.5|c|^2
    __shared__ int   sidx[512];           // 2 KB

    const int t = threadIdx.x;
    const int row0 = blockIdx.x * 512;

    // stage codebook + cbias (tiny, L2-hot); visibility guaranteed by the
    // barriers inside the z-phase before first use in the score phase
    {
        const float4* src = (const float4*)cb;
        float4* dst = (float4*)cbs;
#pragma unroll
        for (int i = 0; i < 8; ++i) dst[t + i * 256] = src[t + i * 256];
        cbb[t] = cbias[t];
    }

    // ---- z = x @ Wc.T + bc for 2 rows/thread (rows row0+t and row0+256+t) ----
    // (token-identical per-row arithmetic to the R1 kernel -> bit-identical z)
    float z[2][CODE_D];
#pragma unroll
    for (int j = 0; j < CODE_D; ++j) { const float b = bc[j]; z[0][j] = b; z[1][j] = b; }

    const int rr = t >> 3;  // 0..31 staging row group
    const int qq = t & 7;   // 0..7  staging quad within row
#pragma unroll
    for (int h = 0; h < 2; ++h) {
        const int rb = row0 + h * 256;
        for (int kc = 0; kc < 128; kc += KCH) {
            __syncthreads();   // previous tile fully consumed
#pragma unroll
            for (int i = 0; i < 8; ++i) {
                const int r = i * 32 + rr;
                const int g = rb + r;
                float4 v = make_float4(0.f, 0.f, 0.f, 0.f);
                if (g < N)
                    v = *reinterpret_cast<const float4*>(x + (size_t)g * 128 + kc + qq * 4);
                *reinterpret_cast<float4*>(&xs[r * LSTR + qq * 4]) = v;
            }
            __syncthreads();
#pragma unroll
            for (int q = 0; q < KCH / 4; ++q) {
                const float4 xv = *reinterpret_cast<const float4*>(&xs[t * LSTR + q * 4]);
                const int kb = kc + q * 4;
#pragma unroll
                for (int j = 0; j < CODE_D; ++j) {
                    const float* w = Wc + j * 128 + kb;   // block-uniform -> s_load (16 KB fits k$)
                    z[h][j] += w[0] * xv.x + w[1] * xv.y + w[2] * xv.z + w[3] * xv.w;
                }
            }
        }
    }

    // ---- scores: argmax_c (z . C[c] + cbias[c]) ----
    // EXACT R1 arithmetic per row: 4 strided fmac chains, ((s0+s1)+(s2+s3))+bias,
    // sequential first-wins compare. Codebook read from LDS (same bits as global).
    float bestA = -3.0e38f, bestB = -3.0e38f;
    int biA = 0, biB = 0;
#pragma unroll 2
    for (int c = 0; c < NUM_C; ++c) {
        const float* crow = cbs + c * CODE_D;
        float sA0 = 0.f, sA1 = 0.f, sA2 = 0.f, sA3 = 0.f;
        float sB0 = 0.f, sB1 = 0.f, sB2 = 0.f, sB3 = 0.f;
#pragma unroll
        for (int d = 0; d < CODE_D; d += 4) {
            const float c0 = crow[d + 0], c1 = crow[d + 1];
            const float c2 = crow[d + 2], c3 = crow[d + 3];
            sA0 += c0 * z[0][d + 0];
            sA1 += c1 * z[0][d + 1];
            sA2 += c2 * z[0][d + 2];
            sA3 += c3 * z[0][d + 3];
            sB0 += c0 * z[1][d + 0];
            sB1 += c1 * z[1][d + 1];
            sB2 += c2 * z[1][d + 2];
            sB3 += c3 * z[1][d + 3];
        }
        const float bias = cbb[c];
        const float sA = ((sA0 + sA1) + (sA2 + sA3)) + bias;
        const float sB = ((sB0 + sB1) + (sB2 + sB3)) + bias;
        if (sA > bestA) { bestA = sA; biA = c; }
        if (sB > bestB) { bestB = sB; biB = c; }
    }

    sidx[t] = biA;
    sidx[t + 256] = biB;
    if (row0 + t < N) idx_out[row0 + t] = (float)biA;
    if (row0 + 256 + t < N) idx_out[row0 + 256 + t] = (float)biB;
    __syncthreads();

    // ---- cooperative coalesced table-gather store of y (512 rows) ----
    const int rsub = t >> 5;  // 0..7
    const int c4 = t & 31;    // float4 column
#pragma unroll 4
    for (int i = 0; i < 64; ++i) {
        const int r = i * 8 + rsub;
        const int g = row0 + r;
        if (g < N) {
            const int ci = sidx[r];
            const float4 v = *reinterpret_cast<const float4*>(ytab + ci * 128 + c4 * 4);
            *reinterpret_cast<float4*>(y + (size_t)g * 128 + c4 * 4) = v;
        }
    }

    if (blockIdx.x == 0 && t == 0) loss_out[0] = 0.0f;
}

// ---------------- launch -----------------------------------------------------------

extern "C" void kernel_launch(void* const* d_in, const int* in_sizes, int n_in,
                              void* d_out, int out_size, void* d_ws, size_t ws_size,
                              hipStream_t stream) {
    const float* x   = (const float*)d_in[0];
    const float* Wd  = (const float*)d_in[1];
    const float* bd  = (const float*)d_in[2];
    const float* Wp  = (const float*)d_in[3];
    const float* bp  = (const float*)d_in[4];
    const float* cb  = (const float*)d_in[5];
    const float* Wpo = (const float*)d_in[6];
    const float* bpo = (const float*)d_in[7];
    const float* Wu  = (const float*)d_in[8];
    const float* bu  = (const float*)d_in[9];

    const int N = in_sizes[0] / 128;

    // ws layout (floats): Wc[4096] | bc[32] | cbias[256] | ytab[32768]
    float* ws    = (float*)d_ws;
    float* Wc    = ws;
    float* bc    = ws + 4096;
    float* cbias = ws + 4128;
    float* ytab  = ws + 4384;

    float* y    = (float*)d_out;
    float* idxf = y + (size_t)N * 128;
    float* loss = idxf + N;

    vq_prep1<<<17, 256, 0, stream>>>(Wd, bd, Wp, bp, cb, Wc, bc, cbias);
    vq_prep2<<<NUM_C, 128, 0, stream>>>(cb, Wpo, bpo, Wu, bu, ytab);

    const int blocks = (N + 511) / 512;
    vq_main<<<blocks, 256, 0, stream>>>(x, Wc, bc, cb, cbias, ytab, y, idxf, loss, N);
}